// Round 1
// baseline (1926.446 us; speedup 1.0000x reference)
//
#include <hip/hip_runtime.h>
#include <stdint.h>

#define H 256
#define E 128
#define BATCH 64
#define SLEN 128
#define TLEN 64
#define VOCAB 32000
#define GATES 1024   // 4*H

typedef __attribute__((ext_vector_type(8))) short bf16x8;
typedef __attribute__((ext_vector_type(4))) float f32x4;
typedef __attribute__((ext_vector_type(4))) unsigned short u16x4;
typedef __attribute__((ext_vector_type(8))) unsigned short u16x8;

union BF8 { unsigned short u[8]; bf16x8 v; };

static __device__ __forceinline__ unsigned short f2bf(float f) {
  unsigned u = __builtin_bit_cast(unsigned, f);
  unsigned r = u + 0x7fffu + ((u >> 16) & 1u);
  return (unsigned short)(r >> 16);
}
static __device__ __forceinline__ float bf2f(unsigned short h) {
  unsigned u = ((unsigned)h) << 16;
  return __builtin_bit_cast(float, u);
}
static __device__ __forceinline__ float sigf(float x) {
  return 1.0f / (1.0f + __expf(-x));
}
static __device__ __forceinline__ float tanh_fast(float x) {
  float a = fabsf(x);
  float e = __expf(-2.0f * a);
  float t = (1.0f - e) / (1.0f + e);
  return x < 0.0f ? -t : t;
}

// ---------------------------------------------------------------- zero out[:,0,:]
__global__ __launch_bounds__(256) void zero_t0(float* __restrict__ out) {
  int b = blockIdx.y;
  int i = (blockIdx.x * 256 + threadIdx.x) * 4;
  if (i < VOCAB) {
    float4 z = {0.f, 0.f, 0.f, 0.f};
    *(float4*)(out + (size_t)b * TLEN * VOCAB + i) = z;
  }
}

// ---------------------------------------------------------------- fp32 -> bf16
__global__ __launch_bounds__(256) void cvt_bf16(const float* __restrict__ in,
                                                unsigned short* __restrict__ out,
                                                long n) {
  long i = ((long)blockIdx.x * 256 + threadIdx.x) * 4;
  if (i < n) {
    float4 v = *(const float4*)(in + i);
    u16x4 o;
    o.x = f2bf(v.x); o.y = f2bf(v.y); o.z = f2bf(v.z); o.w = f2bf(v.w);
    *(u16x4*)(out + i) = o;
  }
}

// ---------------------------------------------------------------- Xg = emb[tok] @ Wih^T + b
// grid: (16 n-tiles of 64 gate cols, nsteps). block 256 = 4 waves.
// Xg layout: [step][batch 64][1024] bf16
__global__ __launch_bounds__(256) void xg_kernel(const int* __restrict__ toks, int tok_stride,
                                                 const float* __restrict__ emb,
                                                 const float* __restrict__ Wih,
                                                 const float* __restrict__ bias,
                                                 unsigned short* __restrict__ Xg) {
  int step = blockIdx.y;
  int tN = blockIdx.x;
  int tid = threadIdx.x, wave = tid >> 6, lane = tid & 63;
  __shared__ unsigned short As[64 * 136];  // batch x E (pad 128->136)
  __shared__ unsigned short Bs[64 * 136];  // gate-rows x E

  // stage A: 64 rows x 32 segs of 4 floats
  for (int s_ = tid; s_ < 2048; s_ += 256) {
    int b = s_ >> 5, seg = s_ & 31;
    int tok = toks[b * tok_stride + step];
    float4 v = *(const float4*)(emb + (size_t)tok * E + seg * 4);
    u16x4 o;
    o.x = f2bf(v.x); o.y = f2bf(v.y); o.z = f2bf(v.z); o.w = f2bf(v.w);
    *(u16x4*)&As[b * 136 + seg * 4] = o;
  }
  // stage B: Wih rows tN*64..+63
  for (int s_ = tid; s_ < 2048; s_ += 256) {
    int r = s_ >> 5, seg = s_ & 31;
    float4 v = *(const float4*)(Wih + (size_t)(tN * 64 + r) * E + seg * 4);
    u16x4 o;
    o.x = f2bf(v.x); o.y = f2bf(v.y); o.z = f2bf(v.z); o.w = f2bf(v.w);
    *(u16x4*)&Bs[r * 136 + seg * 4] = o;
  }
  __syncthreads();

  f32x4 acc[4];
  for (int i = 0; i < 4; ++i) acc[i] = (f32x4){0.f, 0.f, 0.f, 0.f};
#pragma unroll
  for (int kk = 0; kk < 4; ++kk) {
    bf16x8 bf = *(const bf16x8*)&Bs[(wave * 16 + (lane & 15)) * 136 + kk * 32 + ((lane >> 4) << 3)];
#pragma unroll
    for (int mt = 0; mt < 4; ++mt) {
      bf16x8 af = *(const bf16x8*)&As[(mt * 16 + (lane & 15)) * 136 + kk * 32 + ((lane >> 4) << 3)];
      acc[mt] = __builtin_amdgcn_mfma_f32_16x16x32_bf16(af, bf, acc[mt], 0, 0, 0);
    }
  }
  int ncol = tN * 64 + wave * 16 + (lane & 15);
  float bv = bias[ncol];
#pragma unroll
  for (int mt = 0; mt < 4; ++mt)
#pragma unroll
    for (int r = 0; r < 4; ++r) {
      int b = mt * 16 + ((lane >> 4) << 2) + r;
      Xg[((size_t)step * 64 + b) * GATES + ncol] = f2bf(acc[mt][r] + bv);
    }
}

// ---------------------------------------------------------------- recurrence
// 8 blocks x 512 thr (8 waves). block bk owns hidden slice [bk*32, bk*32+32)
// => 128 Whh rows (4 gates x 32), held as register B-fragments.
__global__ __launch_bounds__(512, 1) void rec_kernel(const unsigned short* __restrict__ XgEnc,
                                                     const unsigned short* __restrict__ XgDec,
                                                     const float* __restrict__ encWhh,
                                                     const float* __restrict__ decWhh,
                                                     unsigned short* __restrict__ hbuf,   // 2*64*256 bf16
                                                     unsigned short* __restrict__ hsOut,  // 63*64*256 bf16
                                                     unsigned* __restrict__ barCnt) {
  extern __shared__ char smem_raw[];
  unsigned short* hcur = (unsigned short*)smem_raw;          // 64 x 264 bf16
  float* gbuf = (float*)(smem_raw + 64 * 264 * 2);           // 64 x 132 f32
  float* cst = gbuf + 64 * 132;                              // 64 x 32 f32

  int bk = blockIdx.x, tid = threadIdx.x, wave = tid >> 6, lane = tid & 63;

  for (int i = tid; i < 64 * 264; i += 512) hcur[i] = 0;
  for (int i = tid; i < 64 * 32; i += 512) cst[i] = 0.f;

  int nloc = wave * 16 + (lane & 15);                 // local gate col 0..127
  int gcol = ((nloc >> 5) * H) + bk * 32 + (nloc & 31);  // global gate col 0..1023
  int parity = 0;
  unsigned iter = 0;

  for (int phase = 0; phase < 2; ++phase) {
    const float* Whh = phase ? decWhh : encWhh;
    const unsigned short* Xg = phase ? XgDec : XgEnc;
    int L = phase ? (TLEN - 1) : SLEN;

    // load this wave's Whh rows into register B-fragments (fp32 -> bf16)
    bf16x8 wf[8];
    {
      const float* wrow = Whh + (size_t)gcol * H;
#pragma unroll
      for (int kk = 0; kk < 8; ++kk) {
        int k0 = kk * 32 + ((lane >> 4) << 3);
        float4 a = *(const float4*)(wrow + k0);
        float4 b = *(const float4*)(wrow + k0 + 4);
        BF8 tmp;
        tmp.u[0] = f2bf(a.x); tmp.u[1] = f2bf(a.y); tmp.u[2] = f2bf(a.z); tmp.u[3] = f2bf(a.w);
        tmp.u[4] = f2bf(b.x); tmp.u[5] = f2bf(b.y); tmp.u[6] = f2bf(b.z); tmp.u[7] = f2bf(b.w);
        wf[kk] = tmp.v;
      }
    }
    __syncthreads();

    for (int t = 0; t < L; ++t) {
      f32x4 acc[4];
      for (int i = 0; i < 4; ++i) acc[i] = (f32x4){0.f, 0.f, 0.f, 0.f};
#pragma unroll
      for (int kk = 0; kk < 8; ++kk)
#pragma unroll
        for (int mt = 0; mt < 4; ++mt) {
          bf16x8 af = *(const bf16x8*)&hcur[(mt * 16 + (lane & 15)) * 264 + kk * 32 + ((lane >> 4) << 3)];
          acc[mt] = __builtin_amdgcn_mfma_f32_16x16x32_bf16(af, wf[kk], acc[mt], 0, 0, 0);
        }
      // add precomputed input projection, park preactivations in LDS
      const unsigned short* xg_t = Xg + (size_t)t * 64 * GATES;
#pragma unroll
      for (int mt = 0; mt < 4; ++mt)
#pragma unroll
        for (int r = 0; r < 4; ++r) {
          int m = mt * 16 + ((lane >> 4) << 2) + r;
          gbuf[m * 132 + nloc] = acc[mt][r] + bf2f(xg_t[(size_t)m * GATES + gcol]);
        }
      __syncthreads();

      // elementwise gate math: 64 batch x 32 hidden = 2048 cells
      for (int pi = tid; pi < 2048; pi += 512) {
        int b = pi >> 5, jj = pi & 31;
        float gi = gbuf[b * 132 + jj];
        float gf = gbuf[b * 132 + 32 + jj];
        float gg = gbuf[b * 132 + 64 + jj];
        float go = gbuf[b * 132 + 96 + jj];
        float c = sigf(gf) * cst[b * 32 + jj] + sigf(gi) * tanh_fast(gg);
        float hv = sigf(go) * tanh_fast(c);
        cst[b * 32 + jj] = c;
        unsigned short hb = f2bf(hv);
        hbuf[((size_t)((parity ^ 1) * 64 + b)) * H + bk * 32 + jj] = hb;
        if (phase == 1) hsOut[((size_t)t * 64 + b) * H + bk * 32 + jj] = hb;
      }

      // device barrier (monotonic counter; 8 blocks always co-resident)
      __syncthreads();
      if (tid == 0) {
        __threadfence();
        __hip_atomic_fetch_add(barCnt, 1u, __ATOMIC_ACQ_REL, __HIP_MEMORY_SCOPE_AGENT);
        unsigned target = 8u * (iter + 1u);
        while (__hip_atomic_load(barCnt, __ATOMIC_ACQUIRE, __HIP_MEMORY_SCOPE_AGENT) < target) {
          __builtin_amdgcn_s_sleep(1);
        }
      }
      __syncthreads();
      ++iter;
      parity ^= 1;

      // reload full h_{t+1} (64 x 256 bf16) into LDS
      for (int s_ = tid; s_ < 2048; s_ += 512) {
        int row = s_ >> 5, seg = s_ & 31;
        *(u16x8*)&hcur[row * 264 + seg * 8] =
            *(const u16x8*)&hbuf[((size_t)(parity * 64 + row)) * H + seg * 8];
      }
      __syncthreads();
    }
  }
}

// ---------------------------------------------------------------- FC: logits = hs @ fcW^T + b
// grid (500 n-tiles of 64 vocab cols, 63 dec steps). block 256 = 4 waves.
__global__ __launch_bounds__(256) void fc_kernel(const unsigned short* __restrict__ hs,
                                                 const unsigned short* __restrict__ fcW,
                                                 const float* __restrict__ fcb,
                                                 float* __restrict__ out) {
  int tN = blockIdx.x;
  int t = blockIdx.y;
  int tid = threadIdx.x, wave = tid >> 6, lane = tid & 63;
  __shared__ unsigned short As[64 * 264];

  // prefetch B-fragments straight from global (bf16, L2/L3 resident)
  int v = tN * 64 + wave * 16 + (lane & 15);
  const unsigned short* wrow = fcW + (size_t)v * H;
  bf16x8 wf[8];
#pragma unroll
  for (int kk = 0; kk < 8; ++kk)
    wf[kk] = *(const bf16x8*)(wrow + kk * 32 + ((lane >> 4) << 3));

  // stage A-tile (64 x 256 bf16)
  for (int s_ = tid; s_ < 2048; s_ += 256) {
    int r = s_ >> 5, seg = s_ & 31;
    *(u16x8*)&As[r * 264 + seg * 8] = *(const u16x8*)&hs[((size_t)t * 64 + r) * H + seg * 8];
  }
  __syncthreads();

  f32x4 acc[4];
  for (int i = 0; i < 4; ++i) acc[i] = (f32x4){0.f, 0.f, 0.f, 0.f};
#pragma unroll
  for (int kk = 0; kk < 8; ++kk)
#pragma unroll
    for (int mt = 0; mt < 4; ++mt) {
      bf16x8 af = *(const bf16x8*)&As[(mt * 16 + (lane & 15)) * 264 + kk * 32 + ((lane >> 4) << 3)];
      acc[mt] = __builtin_amdgcn_mfma_f32_16x16x32_bf16(af, wf[kk], acc[mt], 0, 0, 0);
    }

  float bv = fcb[v];
#pragma unroll
  for (int mt = 0; mt < 4; ++mt)
#pragma unroll
    for (int r = 0; r < 4; ++r) {
      int b = mt * 16 + ((lane >> 4) << 2) + r;
      out[(size_t)b * TLEN * VOCAB + (size_t)(t + 1) * VOCAB + v] = acc[mt][r] + bv;
    }
}

// ---------------------------------------------------------------- launch
extern "C" void kernel_launch(void* const* d_in, const int* in_sizes, int n_in,
                              void* d_out, int out_size, void* d_ws, size_t ws_size,
                              hipStream_t stream) {
  const int* src = (const int*)d_in[0];
  const int* tgt = (const int*)d_in[1];
  const float* enc_emb = (const float*)d_in[2];
  const float* enc_Wih = (const float*)d_in[3];
  const float* enc_Whh = (const float*)d_in[4];
  const float* enc_b = (const float*)d_in[5];
  const float* dec_emb = (const float*)d_in[6];
  const float* dec_Wih = (const float*)d_in[7];
  const float* dec_Whh = (const float*)d_in[8];
  const float* dec_b = (const float*)d_in[9];
  const float* fc_W = (const float*)d_in[10];
  const float* fc_b = (const float*)d_in[11];
  float* out = (float*)d_out;

  char* ws = (char*)d_ws;
  unsigned short* XgEnc = (unsigned short*)(ws + 0);          // 128*64*1024*2 = 16,777,216
  unsigned short* XgDec = (unsigned short*)(ws + 16777216);   // 63*64*1024*2  =  8,257,536
  unsigned short* fcWbf = (unsigned short*)(ws + 25034752);   // 32000*256*2   = 16,384,000
  unsigned short* hsBuf = (unsigned short*)(ws + 41418752);   // 63*64*256*2   =  2,064,384
  unsigned short* hbuf = (unsigned short*)(ws + 43483136);    // 2*64*256*2    =     65,536
  unsigned* flags = (unsigned*)(ws + 43548672);               // barrier counter

  hipMemsetAsync(flags, 0, 256, stream);
  zero_t0<<<dim3(32, 64), 256, 0, stream>>>(out);
  cvt_bf16<<<dim3(8000), 256, 0, stream>>>(fc_W, fcWbf, (long)VOCAB * H);
  xg_kernel<<<dim3(16, SLEN), 256, 0, stream>>>(src, SLEN, enc_emb, enc_Wih, enc_b, XgEnc);
  xg_kernel<<<dim3(16, TLEN - 1), 256, 0, stream>>>(tgt, TLEN, dec_emb, dec_Wih, dec_b, XgDec);
  rec_kernel<<<dim3(8), 512, 75776, stream>>>(XgEnc, XgDec, enc_Whh, dec_Whh, hbuf, hsBuf, flags);
  fc_kernel<<<dim3(500, 63), 256, 0, stream>>>(hsBuf, fcWbf, fc_b, out);
}